// Round 2
// baseline (410.966 us; speedup 1.0000x reference)
//
#include <hip/hip_runtime.h>

#define HW_ 65536
#define W_ 1024
#define H_ 64
#define B_ 2
#define C_ 68
#define NPIX 131072
#define NBLK 512
#define EPS 1e-5f

typedef __attribute__((ext_vector_type(8))) short short8;
typedef __attribute__((ext_vector_type(4))) float floatx4;

__device__ __forceinline__ unsigned short f2bf(float f) {
  unsigned u = __float_as_uint(f);
  u += 0x7fffu + ((u >> 16) & 1u);
  return (unsigned short)(u >> 16);
}
__device__ __forceinline__ unsigned pack2(float a, float b) {
  return (unsigned)f2bf(a) | ((unsigned)f2bf(b) << 16);
}
__device__ __forceinline__ float wred(float v) {
  v += __shfl_xor(v, 1);  v += __shfl_xor(v, 2);  v += __shfl_xor(v, 4);
  v += __shfl_xor(v, 8);  v += __shfl_xor(v, 16); v += __shfl_xor(v, 32);
  return v;
}
__device__ __forceinline__ int swz_tile(int bid) {
  // XCD-contiguous: XCD j (= bid%8) owns tiles [j*64, j*64+64)
  return (bid & 7) * 64 + (bid >> 3);
}
// device-scope coherent read of a workspace scalar (per-XCD L2 not coherent
// within a single kernel -- plain loads could be stale after the barrier)
__device__ __forceinline__ float wsld(const float* p) {
  return __hip_atomic_load(p, __ATOMIC_RELAXED, __HIP_MEMORY_SCOPE_AGENT);
}

// Sense-reversing grid barrier. bar[0]=arrive count, bar[1]=generation.
// Requires all NBLK blocks co-resident (LDS 70.9KB -> 2 blk/CU, 512 = 256CU*2).
// Bounded spin: if co-residency ever breaks we produce a wrong answer, not a hang.
__device__ __forceinline__ void gridbar(unsigned* bar) {
  __syncthreads();
  if (threadIdx.x == 0) {
    __threadfence();  // prior global writes (atomicAdds) visible device-wide
    unsigned gen = __hip_atomic_load(&bar[1], __ATOMIC_RELAXED, __HIP_MEMORY_SCOPE_AGENT);
    unsigned arrived =
        __hip_atomic_fetch_add(&bar[0], 1u, __ATOMIC_ACQ_REL, __HIP_MEMORY_SCOPE_AGENT);
    if (arrived == NBLK - 1) {
      __hip_atomic_store(&bar[0], 0u, __ATOMIC_RELAXED, __HIP_MEMORY_SCOPE_AGENT);
      __hip_atomic_store(&bar[1], gen + 1u, __ATOMIC_RELEASE, __HIP_MEMORY_SCOPE_AGENT);
    } else {
      long long spins = 0;
      while (__hip_atomic_load(&bar[1], __ATOMIC_ACQUIRE, __HIP_MEMORY_SCOPE_AGENT) == gen) {
        if (++spins > (1LL << 22)) break;  // ~1s safety valve
        __builtin_amdgcn_s_sleep(8);
      }
    }
    __threadfence();
  }
  __syncthreads();
}

// Single persistent kernel.
// Phase A: neighborhood load (once) -> stats1 sums  -> gridbar
// Phase B: bn1/gbn1 scales -> stats2 sums (register recompute, no loads) -> gridbar
// Phase C: softmax weights + g-vec + fagg gather + MFMA GEMM + abn sums -> gridbar
// Phase D: abn apply from registers -> store out directly (no out_pre round-trip).
__global__ __launch_bounds__(256, 2) void k_all(
    const float* __restrict__ x, const float* __restrict__ mask,
    const float* __restrict__ w1, const float* __restrict__ bn1_g,
    const float* __restrict__ bn1_b, const float* __restrict__ w2,
    const float* __restrict__ b2, const float* __restrict__ g1,
    const float* __restrict__ gbn1_g, const float* __restrict__ gbn1_b,
    const float* __restrict__ g2, const float* __restrict__ gbn2_g,
    const float* __restrict__ gbn2_b, const float* __restrict__ w_agg,
    const float* __restrict__ abn_g, const float* __restrict__ abn_b,
    float* __restrict__ ws, float* __restrict__ out) {
  unsigned* bar = (unsigned*)(ws + 248);

  __shared__ uint4 vecA[17][256];
  __shared__ float red[4][34];
  __shared__ float sA[8], hA[8], sG1[8], hG1[8], sG2[8], hG2[8];
  __shared__ float scD[64], shD[64];

  int tile = swz_tile(blockIdx.x);
  int p0 = tile * 256;
  int p = p0 + (int)threadIdx.x;
  int b = p >> 16, s = p & (HW_ - 1);
  int h = s >> 10, w = s & (W_ - 1);
  const float* xb = x + (size_t)b * C_ * HW_;
  const float* mb = mask + (size_t)b * HW_;
  int lane = threadIdx.x & 63, wave = threadIdx.x >> 6;
  int q = lane >> 4, r = lane & 15;

  float xc0 = xb[s], xc1 = xb[HW_ + s], xc2 = xb[2 * HW_ + s], xc3 = xb[3 * HW_ + s];

  // ---- neighborhood: load once, keep in registers across phases ----
  float pn[9][4];
  int nsv[9];
  unsigned mbits = 0u, ibits = 0u;
  float cntk = 0.f;
#pragma unroll
  for (int k = 0; k < 9; k++) {
    int di = k / 3 - 1, dj = k % 3 - 1;
    int hh = h + di, ww = w + dj;
    bool inb = ((unsigned)hh < (unsigned)H_) && ((unsigned)ww < (unsigned)W_);
    int ns = hh * W_ + ww;
    nsv[k] = ns;
    pn[k][0] = 0.f; pn[k][1] = 0.f; pn[k][2] = 0.f; pn[k][3] = 0.f;
    if (inb) ibits |= (1u << k);
    float mval = inb ? mb[ns] : 0.f;
    if (mval > 0.f) {
      mbits |= (1u << k);
      cntk += 1.f;
      pn[k][0] = xb[ns] - xc0;
      pn[k][1] = xb[HW_ + ns] - xc1;
      pn[k][2] = xb[2 * HW_ + ns] - xc2;
      pn[k][3] = xb[3 * HW_ + ns] - xc3;
    }
  }

  // ---------------- Phase A: stats1 (w1 path + g1 path + counts) ----------
  {
    float acc[34];
#pragma unroll
    for (int i = 0; i < 34; i++) acc[i] = 0.f;
    acc[32] = cntk;
    acc[33] = (mbits & 16u) ? 1.f : 0.f;  // center mask (k==4)
#pragma unroll
    for (int k = 0; k < 9; k++) {
      if ((mbits >> k) & 1u) {
#pragma unroll
        for (int o = 0; o < 8; o++) {
          float ta = pn[k][0] * w1[o * 4] + pn[k][1] * w1[o * 4 + 1] +
                     pn[k][2] * w1[o * 4 + 2] + pn[k][3] * w1[o * 4 + 3];
          acc[o] += ta; acc[8 + o] += ta * ta;
          float tg = pn[k][0] * g1[o * 4] + pn[k][1] * g1[o * 4 + 1] +
                     pn[k][2] * g1[o * 4 + 2] + pn[k][3] * g1[o * 4 + 3];
          acc[16 + o] += tg; acc[24 + o] += tg * tg;
        }
      }
    }
#pragma unroll
    for (int i = 0; i < 34; i++) {
      float rv = wred(acc[i]);
      if (lane == 0) red[wave][i] = rv;
    }
    __syncthreads();
    if (threadIdx.x < 34)
      atomicAdd(&ws[threadIdx.x],
                red[0][threadIdx.x] + red[1][threadIdx.x] + red[2][threadIdx.x] + red[3][threadIdx.x]);
  }
  gridbar(bar);

  // ---------------- Phase B: bn1/gbn1 scales + stats2 ---------------------
  if (threadIdx.x < 16) {
    int o = threadIdx.x & 7;
    float n = fmaxf(wsld(&ws[32]), 1.f);
    float sum, sum2, gma, bta;
    if (threadIdx.x < 8) { sum = wsld(&ws[o]);      sum2 = wsld(&ws[8 + o]);  gma = bn1_g[o];  bta = bn1_b[o]; }
    else                 { sum = wsld(&ws[16 + o]); sum2 = wsld(&ws[24 + o]); gma = gbn1_g[o]; bta = gbn1_b[o]; }
    float mean = sum / n, var = sum2 / n - mean * mean;
    float sc_ = gma * rsqrtf(var + EPS);
    float sh_ = bta - mean * sc_;
    if (threadIdx.x < 8) { sA[o] = sc_;  hA[o] = sh_; }
    else                 { sG1[o] = sc_; hG1[o] = sh_; }
  }
  __syncthreads();
  {
    float acc2[16];
#pragma unroll
    for (int i = 0; i < 16; i++) acc2[i] = 0.f;
#pragma unroll
    for (int k = 0; k < 9; k++) {
      if ((mbits >> k) & 1u) {
        float gb[8];
#pragma unroll
        for (int o = 0; o < 8; o++) {
          float tg = pn[k][0] * g1[o * 4] + pn[k][1] * g1[o * 4 + 1] +
                     pn[k][2] * g1[o * 4 + 2] + pn[k][3] * g1[o * 4 + 3];
          gb[o] = fmaxf(sG1[o] * tg + hG1[o], 0.f);
        }
#pragma unroll
        for (int j = 0; j < 8; j++) {
          float t2 = 0.f;
#pragma unroll
          for (int o = 0; o < 8; o++) t2 += gb[o] * g2[j * 8 + o];
          acc2[j] += t2; acc2[8 + j] += t2 * t2;
        }
      }
    }
#pragma unroll
    for (int i = 0; i < 16; i++) {
      float rv = wred(acc2[i]);
      if (lane == 0) red[wave][i] = rv;
    }
    __syncthreads();
    if (threadIdx.x < 16)
      atomicAdd(&ws[40 + threadIdx.x],
                red[0][threadIdx.x] + red[1][threadIdx.x] + red[2][threadIdx.x] + red[3][threadIdx.x]);
  }
  gridbar(bar);

  // ---------------- Phase C: fused softmax/g-vec/fagg + MFMA + abn sums ---
  if (threadIdx.x < 8) {
    int o = threadIdx.x;
    float n = fmaxf(wsld(&ws[32]), 1.f);
    float mean = wsld(&ws[40 + o]) / n, var = wsld(&ws[48 + o]) / n - mean * mean;
    float sc_ = gbn2_g[o] * rsqrtf(var + EPS);
    sG2[o] = sc_; hG2[o] = gbn2_b[o] - mean * sc_;
  }
  __syncthreads();

  float b2v = b2[0];
  float ev[9];
  float mx = -1e30f;
#pragma unroll
  for (int k = 0; k < 9; k++) {
    float wp = 0.f;
    if ((mbits >> k) & 1u) {
      float accw = 0.f;
#pragma unroll
      for (int o = 0; o < 8; o++) {
        float ta = pn[k][0] * w1[o * 4] + pn[k][1] * w1[o * 4 + 1] +
                   pn[k][2] * w1[o * 4 + 2] + pn[k][3] * w1[o * 4 + 3];
        accw += fmaxf(sA[o] * ta + hA[o], 0.f) * w2[o];
      }
      wp = accw + b2v;
    }
    ev[k] = wp;
    mx = fmaxf(mx, wp);
  }
  float den = 0.f;
#pragma unroll
  for (int k = 0; k < 9; k++) { ev[k] = __expf(ev[k] - mx); den += ev[k]; }
  float inv = 1.f / den;

  // g-vector pack first (pn dies here -> lower pressure in fagg gather)
#pragma unroll
  for (int k = 0; k < 9; k++) {
    float wt = ev[k] * inv;
    uint4 pk; pk.x = pk.y = pk.z = pk.w = 0u;
    if ((mbits >> k) & 1u) {
      float gb[8];
#pragma unroll
      for (int o = 0; o < 8; o++) {
        float tg = pn[k][0] * g1[o * 4] + pn[k][1] * g1[o * 4 + 1] +
                   pn[k][2] * g1[o * 4 + 2] + pn[k][3] * g1[o * 4 + 3];
        gb[o] = fmaxf(sG1[o] * tg + hG1[o], 0.f);
      }
      float gv[8];
#pragma unroll
      for (int j = 0; j < 8; j++) {
        float t2 = 0.f;
#pragma unroll
        for (int o = 0; o < 8; o++) t2 += gb[o] * g2[j * 8 + o];
        float gg = fmaxf(sG2[j] * t2 + hG2[j], 0.f);
        gv[j] = wt * gg;
      }
      pk.x = pack2(gv[0], gv[1]); pk.y = pack2(gv[2], gv[3]);
      pk.z = pack2(gv[4], gv[5]); pk.w = pack2(gv[6], gv[7]);
    }
    vecA[8 + k][threadIdx.x] = pk;
  }

  // feature aggregation gather
  float fagg[64];
#pragma unroll
  for (int c = 0; c < 64; c++) fagg[c] = 0.f;
#pragma unroll
  for (int k = 0; k < 9; k++) {
    if ((ibits >> k) & 1u) {
      float wt = ev[k] * inv;
      const float* xf = xb + 4 * HW_ + nsv[k];
#pragma unroll
      for (int c = 0; c < 64; c++) fagg[c] += wt * xf[c * HW_];
    }
  }
#pragma unroll
  for (int c = 0; c < 64; c += 8) {
    uint4 pk;
    pk.x = pack2(fagg[c], fagg[c + 1]);     pk.y = pack2(fagg[c + 2], fagg[c + 3]);
    pk.z = pack2(fagg[c + 4], fagg[c + 5]); pk.w = pack2(fagg[c + 6], fagg[c + 7]);
    vecA[c >> 3][threadIdx.x] = pk;
  }
  __syncthreads();

  // ---- GEMM: D[pixel 256][chan 64] = vecA @ w_agg^T, 16x16x32 bf16 MFMA ----
  short8 Bf[4][5];
#pragma unroll
  for (int nt = 0; nt < 4; nt++) {
    int n = nt * 16 + r;
#pragma unroll
    for (int ks = 0; ks < 5; ks++) {
      int k0 = ks * 32 + q * 8;
      uint4 pk; pk.x = pk.y = pk.z = pk.w = 0u;
      if (k0 < 136) {
        float4 f0 = *reinterpret_cast<const float4*>(w_agg + n * 136 + k0);
        float4 f1 = *reinterpret_cast<const float4*>(w_agg + n * 136 + k0 + 4);
        pk.x = pack2(f0.x, f0.y); pk.y = pack2(f0.z, f0.w);
        pk.z = pack2(f1.x, f1.y); pk.w = pack2(f1.z, f1.w);
      }
      Bf[nt][ks] = *reinterpret_cast<short8*>(&pk);
    }
  }

  floatx4 acc[4][4];
#pragma unroll
  for (int m = 0; m < 4; m++)
#pragma unroll
    for (int nt = 0; nt < 4; nt++) acc[m][nt] = (floatx4){0.f, 0.f, 0.f, 0.f};

#pragma unroll
  for (int m = 0; m < 4; m++) {
    int mt = wave * 4 + m;
    int pix = mt * 16 + r;
    short8 Af[5];
#pragma unroll
    for (int ks = 0; ks < 5; ks++) {
      int chunk = ks * 4 + q;
      if (chunk < 17)
        Af[ks] = *reinterpret_cast<const short8*>(&vecA[chunk][pix]);
      else
        Af[ks] = (short8){0, 0, 0, 0, 0, 0, 0, 0};
    }
#pragma unroll
    for (int nt = 0; nt < 4; nt++)
#pragma unroll
      for (int ks = 0; ks < 5; ks++)
        acc[m][nt] = __builtin_amdgcn_mfma_f32_16x16x32_bf16(Af[ks], Bf[nt][ks], acc[m][nt], 0, 0, 0);
  }

  // masked abn partial sums (out stays in registers)
  float aS[4] = {0.f, 0.f, 0.f, 0.f}, aQ[4] = {0.f, 0.f, 0.f, 0.f};
  int s0 = p0 & (HW_ - 1);
#pragma unroll
  for (int m = 0; m < 4; m++) {
    int mt = wave * 4 + m;
    int srow = s0 + mt * 16 + q * 4;
    float4 mv = *reinterpret_cast<const float4*>(mb + srow);
    float m0 = (mv.x > 0.f) ? 1.f : 0.f, m1 = (mv.y > 0.f) ? 1.f : 0.f;
    float m2 = (mv.z > 0.f) ? 1.f : 0.f, m3 = (mv.w > 0.f) ? 1.f : 0.f;
#pragma unroll
    for (int nt = 0; nt < 4; nt++) {
      aS[nt] += acc[m][nt][0] * m0 + acc[m][nt][1] * m1 + acc[m][nt][2] * m2 + acc[m][nt][3] * m3;
      aQ[nt] += acc[m][nt][0] * acc[m][nt][0] * m0 + acc[m][nt][1] * acc[m][nt][1] * m1 +
                acc[m][nt][2] * acc[m][nt][2] * m2 + acc[m][nt][3] * acc[m][nt][3] * m3;
    }
  }

  __syncthreads();  // all vecA ds_reads done; reuse LDS for reduction
  float* rS = (float*)&vecA[0][0];          // [4][64]
  float* rQ = rS + 256;                     // [4][64]
#pragma unroll
  for (int nt = 0; nt < 4; nt++) {
    float v1 = aS[nt], v2 = aQ[nt];
    v1 += __shfl_xor(v1, 16); v1 += __shfl_xor(v1, 32);
    v2 += __shfl_xor(v2, 16); v2 += __shfl_xor(v2, 32);
    if (lane < 16) { rS[wave * 64 + nt * 16 + lane] = v1; rQ[wave * 64 + nt * 16 + lane] = v2; }
  }
  __syncthreads();
  if (threadIdx.x < 64) {
    atomicAdd(&ws[64 + threadIdx.x],
              rS[threadIdx.x] + rS[64 + threadIdx.x] + rS[128 + threadIdx.x] + rS[192 + threadIdx.x]);
    atomicAdd(&ws[128 + threadIdx.x],
              rQ[threadIdx.x] + rQ[64 + threadIdx.x] + rQ[128 + threadIdx.x] + rQ[192 + threadIdx.x]);
  }
  gridbar(bar);

  // ---------------- Phase D: abn apply + relu + center-mask zero + store --
  if (threadIdx.x < 64) {
    int c = threadIdx.x;
    float n0 = fmaxf(wsld(&ws[33]), 1.f);
    float mean = wsld(&ws[64 + c]) / n0;
    float var = wsld(&ws[128 + c]) / n0 - mean * mean;
    float sc_ = abn_g[c] * rsqrtf(var + EPS);
    scD[c] = sc_; shD[c] = abn_b[c] - mean * sc_;
  }
  __syncthreads();
#pragma unroll
  for (int m = 0; m < 4; m++) {
    int mt = wave * 4 + m;
    int srow = s0 + mt * 16 + q * 4;
    float4 mv = *reinterpret_cast<const float4*>(mb + srow);
#pragma unroll
    for (int nt = 0; nt < 4; nt++) {
      int ch = nt * 16 + r;
      float sc_ = scD[ch], sh_ = shD[ch];
      float4 ov;
      ov.x = (mv.x > 0.f) ? fmaxf(acc[m][nt][0] * sc_ + sh_, 0.f) : 0.f;
      ov.y = (mv.y > 0.f) ? fmaxf(acc[m][nt][1] * sc_ + sh_, 0.f) : 0.f;
      ov.z = (mv.z > 0.f) ? fmaxf(acc[m][nt][2] * sc_ + sh_, 0.f) : 0.f;
      ov.w = (mv.w > 0.f) ? fmaxf(acc[m][nt][3] * sc_ + sh_, 0.f) : 0.f;
      *reinterpret_cast<float4*>(out + ((size_t)(b * 64 + ch)) * HW_ + srow) = ov;
    }
  }
}

extern "C" void kernel_launch(void* const* d_in, const int* in_sizes, int n_in,
                              void* d_out, int out_size, void* d_ws, size_t ws_size,
                              hipStream_t stream) {
  const float* x      = (const float*)d_in[0];
  const float* mask   = (const float*)d_in[1];
  const float* w1     = (const float*)d_in[2];
  const float* bn1_g  = (const float*)d_in[3];
  const float* bn1_b  = (const float*)d_in[4];
  const float* w2     = (const float*)d_in[5];
  const float* b2     = (const float*)d_in[6];
  const float* g1     = (const float*)d_in[7];
  const float* gbn1_g = (const float*)d_in[8];
  const float* gbn1_b = (const float*)d_in[9];
  const float* g2     = (const float*)d_in[10];
  const float* gbn2_g = (const float*)d_in[11];
  const float* gbn2_b = (const float*)d_in[12];
  const float* w_agg  = (const float*)d_in[13];
  const float* abn_g  = (const float*)d_in[14];
  const float* abn_b  = (const float*)d_in[15];
  float* out = (float*)d_out;

  if (ws_size < 1024) return;
  float* wsf = (float*)d_ws;

  // zeroes stats (ws[0..191]) AND barrier state (ws[248..249])
  hipMemsetAsync(d_ws, 0, 1024, stream);

  k_all<<<NBLK, 256, 0, stream>>>(x, mask, w1, bn1_g, bn1_b, w2, b2, g1,
                                  gbn1_g, gbn1_b, g2, gbn2_g, gbn2_b, w_agg,
                                  abn_g, abn_b, wsf, out);
}

// Round 3
// 272.253 us; speedup vs baseline: 1.5095x; 1.5095x over previous
//
#include <hip/hip_runtime.h>

#define HW_ 65536
#define W_ 1024
#define H_ 64
#define B_ 2
#define C_ 68
#define NPIX 131072
#define NBLK 512
#define EPS 1e-5f

typedef __attribute__((ext_vector_type(8))) short short8;
typedef __attribute__((ext_vector_type(4))) float floatx4;

__device__ __forceinline__ unsigned short f2bf(float f) {
  unsigned u = __float_as_uint(f);
  u += 0x7fffu + ((u >> 16) & 1u);
  return (unsigned short)(u >> 16);
}
__device__ __forceinline__ unsigned pack2(float a, float b) {
  return (unsigned)f2bf(a) | ((unsigned)f2bf(b) << 16);
}
__device__ __forceinline__ float wred(float v) {
  v += __shfl_xor(v, 1);  v += __shfl_xor(v, 2);  v += __shfl_xor(v, 4);
  v += __shfl_xor(v, 8);  v += __shfl_xor(v, 16); v += __shfl_xor(v, 32);
  return v;
}
__device__ __forceinline__ int swz_tile(int bid) {
  // XCD-contiguous: XCD j (= bid%8) owns tiles [j*64, j*64+64)
  return (bid & 7) * 64 + (bid >> 3);
}
__device__ __forceinline__ float wsld(const float* p) {
  return __hip_atomic_load(p, __ATOMIC_RELAXED, __HIP_MEMORY_SCOPE_AGENT);
}

// Sense-reversing grid barrier (proven in R2). bar[0]=count, bar[1]=generation.
// k_stats: 256 thr, ~110 VGPR, 680B LDS -> >=2 blocks/CU guaranteed, 512 co-resident.
__device__ __forceinline__ void gridbar(unsigned* bar) {
  __syncthreads();
  if (threadIdx.x == 0) {
    __threadfence();
    unsigned gen = __hip_atomic_load(&bar[1], __ATOMIC_RELAXED, __HIP_MEMORY_SCOPE_AGENT);
    unsigned arrived =
        __hip_atomic_fetch_add(&bar[0], 1u, __ATOMIC_ACQ_REL, __HIP_MEMORY_SCOPE_AGENT);
    if (arrived == NBLK - 1) {
      __hip_atomic_store(&bar[0], 0u, __ATOMIC_RELAXED, __HIP_MEMORY_SCOPE_AGENT);
      __hip_atomic_store(&bar[1], gen + 1u, __ATOMIC_RELEASE, __HIP_MEMORY_SCOPE_AGENT);
    } else {
      long long spins = 0;
      while (__hip_atomic_load(&bar[1], __ATOMIC_ACQUIRE, __HIP_MEMORY_SCOPE_AGENT) == gen) {
        if (++spins > (1LL << 22)) break;  // safety valve
        __builtin_amdgcn_s_sleep(8);
      }
    }
    __threadfence();
  }
  __syncthreads();
}

// ---- K1: stats1 + stats2 fused at HIGH occupancy (tiny LDS, pn in regs) ----
// Phase A: neighborhood gather once -> stats1 sums (w1 & g1 paths + counts)
// gridbar
// Phase B: gbn1 scales -> stats2 sums via pure register recompute (no loads)
__global__ __launch_bounds__(256, 2) void k_stats(
    const float* __restrict__ x, const float* __restrict__ mask,
    const float* __restrict__ w1, const float* __restrict__ g1,
    const float* __restrict__ gbn1_g, const float* __restrict__ gbn1_b,
    const float* __restrict__ g2, float* __restrict__ ws) {
  unsigned* bar = (unsigned*)(ws + 248);
  __shared__ float red[4][34];
  __shared__ float sG1[8], hG1[8];

  int p = swz_tile(blockIdx.x) * 256 + (int)threadIdx.x;
  int b = p >> 16, s = p & (HW_ - 1);
  int h = s >> 10, w = s & (W_ - 1);
  const float* xb = x + (size_t)b * C_ * HW_;
  const float* mb = mask + (size_t)b * HW_;
  int lane = threadIdx.x & 63, wave = threadIdx.x >> 6;

  float xc0 = xb[s], xc1 = xb[HW_ + s], xc2 = xb[2 * HW_ + s], xc3 = xb[3 * HW_ + s];

  float pn[9][4];
  unsigned mbits = 0u;
  float cntk = 0.f;
#pragma unroll
  for (int k = 0; k < 9; k++) {
    int di = k / 3 - 1, dj = k % 3 - 1;
    int hh = h + di, ww = w + dj;
    bool inb = ((unsigned)hh < (unsigned)H_) && ((unsigned)ww < (unsigned)W_);
    int ns = hh * W_ + ww;
    pn[k][0] = 0.f; pn[k][1] = 0.f; pn[k][2] = 0.f; pn[k][3] = 0.f;
    float mval = inb ? mb[ns] : 0.f;
    if (mval > 0.f) {
      mbits |= (1u << k);
      cntk += 1.f;
      pn[k][0] = xb[ns] - xc0;
      pn[k][1] = xb[HW_ + ns] - xc1;
      pn[k][2] = xb[2 * HW_ + ns] - xc2;
      pn[k][3] = xb[3 * HW_ + ns] - xc3;
    }
  }

  // Phase A: stats1
  {
    float acc[34];
#pragma unroll
    for (int i = 0; i < 34; i++) acc[i] = 0.f;
    acc[32] = cntk;
    acc[33] = (mbits & 16u) ? 1.f : 0.f;  // center mask
#pragma unroll
    for (int k = 0; k < 9; k++) {
      if ((mbits >> k) & 1u) {
#pragma unroll
        for (int o = 0; o < 8; o++) {
          float ta = pn[k][0] * w1[o * 4] + pn[k][1] * w1[o * 4 + 1] +
                     pn[k][2] * w1[o * 4 + 2] + pn[k][3] * w1[o * 4 + 3];
          acc[o] += ta; acc[8 + o] += ta * ta;
          float tg = pn[k][0] * g1[o * 4] + pn[k][1] * g1[o * 4 + 1] +
                     pn[k][2] * g1[o * 4 + 2] + pn[k][3] * g1[o * 4 + 3];
          acc[16 + o] += tg; acc[24 + o] += tg * tg;
        }
      }
    }
#pragma unroll
    for (int i = 0; i < 34; i++) {
      float rv = wred(acc[i]);
      if (lane == 0) red[wave][i] = rv;
    }
    __syncthreads();
    if (threadIdx.x < 34)
      atomicAdd(&ws[threadIdx.x],
                red[0][threadIdx.x] + red[1][threadIdx.x] + red[2][threadIdx.x] + red[3][threadIdx.x]);
  }
  gridbar(bar);

  // Phase B: gbn1 scales + stats2 (register recompute, zero loads)
  if (threadIdx.x < 8) {
    int o = threadIdx.x;
    float n = fmaxf(wsld(&ws[32]), 1.f);
    float mean = wsld(&ws[16 + o]) / n;
    float var = wsld(&ws[24 + o]) / n - mean * mean;
    float sc_ = gbn1_g[o] * rsqrtf(var + EPS);
    sG1[o] = sc_; hG1[o] = gbn1_b[o] - mean * sc_;
  }
  __syncthreads();
  {
    float acc2[16];
#pragma unroll
    for (int i = 0; i < 16; i++) acc2[i] = 0.f;
#pragma unroll
    for (int k = 0; k < 9; k++) {
      if ((mbits >> k) & 1u) {
        float gb[8];
#pragma unroll
        for (int o = 0; o < 8; o++) {
          float tg = pn[k][0] * g1[o * 4] + pn[k][1] * g1[o * 4 + 1] +
                     pn[k][2] * g1[o * 4 + 2] + pn[k][3] * g1[o * 4 + 3];
          gb[o] = fmaxf(sG1[o] * tg + hG1[o], 0.f);
        }
#pragma unroll
        for (int j = 0; j < 8; j++) {
          float t2 = 0.f;
#pragma unroll
          for (int o = 0; o < 8; o++) t2 += gb[o] * g2[j * 8 + o];
          acc2[j] += t2; acc2[8 + j] += t2 * t2;
        }
      }
    }
#pragma unroll
    for (int i = 0; i < 16; i++) {
      float rv = wred(acc2[i]);
      if (lane == 0) red[wave][i] = rv;
    }
    __syncthreads();
    if (threadIdx.x < 16)
      atomicAdd(&ws[40 + threadIdx.x],
                red[0][threadIdx.x] + red[1][threadIdx.x] + red[2][threadIdx.x] + red[3][threadIdx.x]);
  }
}

// --------- K2: fused per-pixel vec build (LDS) + MFMA GEMM + abn stats ------
// (byte-identical to the proven 224-us baseline k_fused)
__global__ __launch_bounds__(256) void k_fused(
    const float* __restrict__ x, const float* __restrict__ mask,
    const float* __restrict__ w1, const float* __restrict__ bn1_g,
    const float* __restrict__ bn1_b, const float* __restrict__ w2,
    const float* __restrict__ b2, const float* __restrict__ g1,
    const float* __restrict__ gbn1_g, const float* __restrict__ gbn1_b,
    const float* __restrict__ g2, const float* __restrict__ gbn2_g,
    const float* __restrict__ gbn2_b, const float* __restrict__ w_agg,
    const float* __restrict__ ws, float* __restrict__ out_pre,
    float* __restrict__ wsum) {
  __shared__ uint4 vecA[17][256];
  __shared__ float sA[8], hA[8], sG1[8], hG1[8], sG2[8], hG2[8];

  if (threadIdx.x < 24) {
    int o = threadIdx.x & 7;
    float n = fmaxf(ws[32], 1.f);
    float sum, sum2, gma, bta;
    if (threadIdx.x < 8)       { sum = ws[o];      sum2 = ws[8 + o];  gma = bn1_g[o];  bta = bn1_b[o]; }
    else if (threadIdx.x < 16) { sum = ws[16 + o]; sum2 = ws[24 + o]; gma = gbn1_g[o]; bta = gbn1_b[o]; }
    else                       { sum = ws[40 + o]; sum2 = ws[48 + o]; gma = gbn2_g[o]; bta = gbn2_b[o]; }
    float mean = sum / n, var = sum2 / n - mean * mean;
    float s = gma * rsqrtf(var + EPS);
    float sft = bta - mean * s;
    if (threadIdx.x < 8)       { sA[o] = s;  hA[o] = sft; }
    else if (threadIdx.x < 16) { sG1[o] = s; hG1[o] = sft; }
    else                       { sG2[o] = s; hG2[o] = sft; }
  }
  __syncthreads();

  int tile = swz_tile(blockIdx.x);
  int p0 = tile * 256;
  int p = p0 + threadIdx.x;
  int b = p >> 16, s = p & (HW_ - 1);
  int h = s >> 10, w = s & (W_ - 1);
  const float* xb = x + (size_t)b * C_ * HW_;
  const float* mb = mask + (size_t)b * HW_;
  float xc0 = xb[s], xc1 = xb[HW_ + s], xc2 = xb[2 * HW_ + s], xc3 = xb[3 * HW_ + s];
  float b2v = b2[0];

  float ev[9]; int nsv[9]; bool inbv[9], mselv[9];
  float mx = -1e30f;
#pragma unroll
  for (int k = 0; k < 9; k++) {
    int di = k / 3 - 1, dj = k % 3 - 1;
    int hh = h + di, ww = w + dj;
    bool inb = ((unsigned)hh < (unsigned)H_) && ((unsigned)ww < (unsigned)W_);
    int ns = hh * W_ + ww;
    inbv[k] = inb; nsv[k] = ns;
    float mval = inb ? mb[ns] : 0.f;
    bool msel = mval > 0.f;
    mselv[k] = msel;
    float wp = 0.f;
    if (msel) {
      float pn0 = xb[ns] - xc0;
      float pn1 = xb[HW_ + ns] - xc1;
      float pn2 = xb[2 * HW_ + ns] - xc2;
      float pn3 = xb[3 * HW_ + ns] - xc3;
      float accw = 0.f;
#pragma unroll
      for (int o = 0; o < 8; o++) {
        float ta = pn0 * w1[o * 4] + pn1 * w1[o * 4 + 1] + pn2 * w1[o * 4 + 2] + pn3 * w1[o * 4 + 3];
        accw += fmaxf(sA[o] * ta + hA[o], 0.f) * w2[o];
      }
      wp = accw + b2v;
    }
    ev[k] = wp;
    mx = fmaxf(mx, wp);
  }
  float den = 0.f;
#pragma unroll
  for (int k = 0; k < 9; k++) { ev[k] = __expf(ev[k] - mx); den += ev[k]; }
  float inv = 1.f / den;

  float fagg[64];
#pragma unroll
  for (int c = 0; c < 64; c++) fagg[c] = 0.f;

#pragma unroll
  for (int k = 0; k < 9; k++) {
    float wt = ev[k] * inv;
    int ns = nsv[k];
    uint4 pk; pk.x = pk.y = pk.z = pk.w = 0u;
    if (mselv[k]) {
      float pn0 = xb[ns] - xc0;
      float pn1 = xb[HW_ + ns] - xc1;
      float pn2 = xb[2 * HW_ + ns] - xc2;
      float pn3 = xb[3 * HW_ + ns] - xc3;
      float gb[8];
#pragma unroll
      for (int o = 0; o < 8; o++) {
        float tg = pn0 * g1[o * 4] + pn1 * g1[o * 4 + 1] + pn2 * g1[o * 4 + 2] + pn3 * g1[o * 4 + 3];
        gb[o] = fmaxf(sG1[o] * tg + hG1[o], 0.f);
      }
      float gv[8];
#pragma unroll
      for (int j = 0; j < 8; j++) {
        float t2 = 0.f;
#pragma unroll
        for (int o = 0; o < 8; o++) t2 += gb[o] * g2[j * 8 + o];
        float gg = fmaxf(sG2[j] * t2 + hG2[j], 0.f);
        gv[j] = wt * gg;
      }
      pk.x = pack2(gv[0], gv[1]); pk.y = pack2(gv[2], gv[3]);
      pk.z = pack2(gv[4], gv[5]); pk.w = pack2(gv[6], gv[7]);
    }
    vecA[8 + k][threadIdx.x] = pk;
    if (inbv[k]) {
      const float* xf = xb + 4 * HW_ + ns;
#pragma unroll
      for (int c = 0; c < 64; c++) fagg[c] += wt * xf[c * HW_];
    }
  }
#pragma unroll
  for (int c = 0; c < 64; c += 8) {
    uint4 pk;
    pk.x = pack2(fagg[c], fagg[c + 1]);     pk.y = pack2(fagg[c + 2], fagg[c + 3]);
    pk.z = pack2(fagg[c + 4], fagg[c + 5]); pk.w = pack2(fagg[c + 6], fagg[c + 7]);
    vecA[c >> 3][threadIdx.x] = pk;
  }
  __syncthreads();

  int lane = threadIdx.x & 63, wave = threadIdx.x >> 6;
  int q = lane >> 4, r = lane & 15;

  short8 Bf[4][5];
#pragma unroll
  for (int nt = 0; nt < 4; nt++) {
    int n = nt * 16 + r;
#pragma unroll
    for (int ks = 0; ks < 5; ks++) {
      int k0 = ks * 32 + q * 8;
      uint4 pk; pk.x = pk.y = pk.z = pk.w = 0u;
      if (k0 < 136) {
        float4 f0 = *reinterpret_cast<const float4*>(w_agg + n * 136 + k0);
        float4 f1 = *reinterpret_cast<const float4*>(w_agg + n * 136 + k0 + 4);
        pk.x = pack2(f0.x, f0.y); pk.y = pack2(f0.z, f0.w);
        pk.z = pack2(f1.x, f1.y); pk.w = pack2(f1.z, f1.w);
      }
      Bf[nt][ks] = *reinterpret_cast<short8*>(&pk);
    }
  }

  floatx4 acc[4][4];
#pragma unroll
  for (int m = 0; m < 4; m++)
#pragma unroll
    for (int nt = 0; nt < 4; nt++) acc[m][nt] = (floatx4){0.f, 0.f, 0.f, 0.f};

#pragma unroll
  for (int m = 0; m < 4; m++) {
    int mt = wave * 4 + m;
    int pix = mt * 16 + r;
    short8 Af[5];
#pragma unroll
    for (int ks = 0; ks < 5; ks++) {
      int chunk = ks * 4 + q;
      if (chunk < 17)
        Af[ks] = *reinterpret_cast<const short8*>(&vecA[chunk][pix]);
      else
        Af[ks] = (short8){0, 0, 0, 0, 0, 0, 0, 0};
    }
#pragma unroll
    for (int nt = 0; nt < 4; nt++)
#pragma unroll
      for (int ks = 0; ks < 5; ks++)
        acc[m][nt] = __builtin_amdgcn_mfma_f32_16x16x32_bf16(Af[ks], Bf[nt][ks], acc[m][nt], 0, 0, 0);
  }

  float aS[4] = {0.f, 0.f, 0.f, 0.f}, aQ[4] = {0.f, 0.f, 0.f, 0.f};
  int s0 = p0 & (HW_ - 1);
#pragma unroll
  for (int m = 0; m < 4; m++) {
    int mt = wave * 4 + m;
    int srow = s0 + mt * 16 + q * 4;
    float4 mv = *reinterpret_cast<const float4*>(mb + srow);
    float m0 = (mv.x > 0.f) ? 1.f : 0.f, m1 = (mv.y > 0.f) ? 1.f : 0.f;
    float m2 = (mv.z > 0.f) ? 1.f : 0.f, m3 = (mv.w > 0.f) ? 1.f : 0.f;
#pragma unroll
    for (int nt = 0; nt < 4; nt++) {
      int ch = nt * 16 + r;
      float4 ov;
      ov.x = acc[m][nt][0]; ov.y = acc[m][nt][1];
      ov.z = acc[m][nt][2]; ov.w = acc[m][nt][3];
      aS[nt] += ov.x * m0 + ov.y * m1 + ov.z * m2 + ov.w * m3;
      aQ[nt] += ov.x * ov.x * m0 + ov.y * ov.y * m1 + ov.z * ov.z * m2 + ov.w * ov.w * m3;
      *reinterpret_cast<float4*>(out_pre + ((size_t)(b * 64 + ch)) * HW_ + srow) = ov;
    }
  }

  __syncthreads();
  float* rS = (float*)&vecA[0][0];
  float* rQ = rS + 256;
#pragma unroll
  for (int nt = 0; nt < 4; nt++) {
    float v1 = aS[nt], v2 = aQ[nt];
    v1 += __shfl_xor(v1, 16); v1 += __shfl_xor(v1, 32);
    v2 += __shfl_xor(v2, 16); v2 += __shfl_xor(v2, 32);
    if (lane < 16) { rS[wave * 64 + nt * 16 + lane] = v1; rQ[wave * 64 + nt * 16 + lane] = v2; }
  }
  __syncthreads();
  if (threadIdx.x < 64) {
    atomicAdd(&wsum[64 + threadIdx.x],
              rS[threadIdx.x] + rS[64 + threadIdx.x] + rS[128 + threadIdx.x] + rS[192 + threadIdx.x]);
    atomicAdd(&wsum[128 + threadIdx.x],
              rQ[threadIdx.x] + rQ[64 + threadIdx.x] + rQ[128 + threadIdx.x] + rQ[192 + threadIdx.x]);
  }
}

// ---------------- K3: abn apply + relu + center-mask zero -------------------
__global__ __launch_bounds__(256) void k_final(
    const float* __restrict__ out_pre, const float* __restrict__ mask,
    const float* __restrict__ abn_g, const float* __restrict__ abn_b,
    const float* __restrict__ ws, float* __restrict__ out) {
  __shared__ float sc[64], sh[64];
  if (threadIdx.x < 64) {
    int c = threadIdx.x;
    float n0 = fmaxf(ws[33], 1.f);
    float mean = ws[64 + c] / n0;
    float var = ws[128 + c] / n0 - mean * mean;
    float s = abn_g[c] * rsqrtf(var + EPS);
    sc[c] = s; sh[c] = abn_b[c] - mean * s;
  }
  __syncthreads();
  int i4 = (blockIdx.x * 256 + threadIdx.x) * 4;
  if (i4 >= B_ * 64 * HW_) return;
  int c = (i4 >> 16) & 63;
  int b = i4 >> 22;
  int s = i4 & (HW_ - 1);
  float4 v = *reinterpret_cast<const float4*>(out_pre + i4);
  float4 m = *reinterpret_cast<const float4*>(mask + (size_t)b * HW_ + s);
  float4 o;
  o.x = (m.x > 0.f) ? fmaxf(v.x * sc[c] + sh[c], 0.f) : 0.f;
  o.y = (m.y > 0.f) ? fmaxf(v.y * sc[c] + sh[c], 0.f) : 0.f;
  o.z = (m.z > 0.f) ? fmaxf(v.z * sc[c] + sh[c], 0.f) : 0.f;
  o.w = (m.w > 0.f) ? fmaxf(v.w * sc[c] + sh[c], 0.f) : 0.f;
  *reinterpret_cast<float4*>(out + i4) = o;
}

extern "C" void kernel_launch(void* const* d_in, const int* in_sizes, int n_in,
                              void* d_out, int out_size, void* d_ws, size_t ws_size,
                              hipStream_t stream) {
  const float* x      = (const float*)d_in[0];
  const float* mask   = (const float*)d_in[1];
  const float* w1     = (const float*)d_in[2];
  const float* bn1_g  = (const float*)d_in[3];
  const float* bn1_b  = (const float*)d_in[4];
  const float* w2     = (const float*)d_in[5];
  const float* b2     = (const float*)d_in[6];
  const float* g1     = (const float*)d_in[7];
  const float* gbn1_g = (const float*)d_in[8];
  const float* gbn1_b = (const float*)d_in[9];
  const float* g2     = (const float*)d_in[10];
  const float* gbn2_g = (const float*)d_in[11];
  const float* gbn2_b = (const float*)d_in[12];
  const float* w_agg  = (const float*)d_in[13];
  const float* abn_g  = (const float*)d_in[14];
  const float* abn_b  = (const float*)d_in[15];
  float* out = (float*)d_out;

  size_t need = 1024 + (size_t)NPIX * 64 * 4;
  if (ws_size < need) return;

  float* wsf = (float*)d_ws;
  float* out_pre = (float*)((char*)d_ws + 1024);

  // zeroes stats (ws[0..191]) AND barrier state (ws[248..249])
  hipMemsetAsync(d_ws, 0, 1024, stream);
  k_stats<<<NBLK, 256, 0, stream>>>(x, mask, w1, g1, gbn1_g, gbn1_b, g2, wsf);
  k_fused<<<NBLK, 256, 0, stream>>>(x, mask, w1, bn1_g, bn1_b, w2, b2, g1,
                                    gbn1_g, gbn1_b, g2, gbn2_g, gbn2_b, w_agg,
                                    wsf, out_pre, wsf);
  k_final<<<8192, 256, 0, stream>>>(out_pre, mask, abn_g, abn_b, wsf, out);
}

// Round 4
// 208.239 us; speedup vs baseline: 1.9735x; 1.3074x over previous
//
#include <hip/hip_runtime.h>

#define HW_ 65536
#define W_ 1024
#define H_ 64
#define B_ 2
#define C_ 68
#define NPIX 131072
#define EPS 1e-5f

typedef __attribute__((ext_vector_type(8))) short short8;
typedef __attribute__((ext_vector_type(4))) float floatx4;

__device__ __forceinline__ unsigned short f2bf(float f) {
  unsigned u = __float_as_uint(f);
  u += 0x7fffu + ((u >> 16) & 1u);
  return (unsigned short)(u >> 16);
}
__device__ __forceinline__ unsigned pack2(float a, float b) {
  return (unsigned)f2bf(a) | ((unsigned)f2bf(b) << 16);
}
__device__ __forceinline__ float wred(float v) {
  v += __shfl_xor(v, 1);  v += __shfl_xor(v, 2);  v += __shfl_xor(v, 4);
  v += __shfl_xor(v, 8);  v += __shfl_xor(v, 16); v += __shfl_xor(v, 32);
  return v;
}
__device__ __forceinline__ int swz_tile(int bid) {
  // XCD-contiguous: XCD j (= bid%8) owns tiles [j*64, j*64+64)
  return (bid & 7) * 64 + (bid >> 3);
}

// ---- K1: stats1, 2 threads/pixel (blocks 0..511 own k=0..4, 512..1023 k=5..8)
// Block i and 512+i share a tile AND an XCD (same bid%8) -> shared L2 lines.
__global__ __launch_bounds__(256) void k_stats1(
    const float* __restrict__ x, const float* __restrict__ mask,
    const float* __restrict__ w1, const float* __restrict__ g1,
    float* __restrict__ ws) {
  int half = blockIdx.x >> 9;
  int p = swz_tile(blockIdx.x & 511) * 256 + threadIdx.x;
  int b = p >> 16, s = p & (HW_ - 1);
  int h = s >> 10, w = s & (W_ - 1);
  const float* xb = x + (size_t)b * C_ * HW_;
  const float* mb = mask + (size_t)b * HW_;
  float xc0 = xb[s], xc1 = xb[HW_ + s], xc2 = xb[2 * HW_ + s], xc3 = xb[3 * HW_ + s];

  float acc[34];
#pragma unroll
  for (int i = 0; i < 34; i++) acc[i] = 0.f;
  if (half == 0) acc[33] = (mb[s] > 0.f) ? 1.f : 0.f;  // center mask (counted once)

#pragma unroll
  for (int k = 0; k < 9; k++) {
    bool mine = (k < 5) ? (half == 0) : (half == 1);
    if (!mine) continue;
    int di = k / 3 - 1, dj = k % 3 - 1;
    int hh = h + di, ww = w + dj;
    bool inb = ((unsigned)hh < (unsigned)H_) && ((unsigned)ww < (unsigned)W_);
    int ns = hh * W_ + ww;
    float mval = inb ? mb[ns] : 0.f;
    if (mval > 0.f) {
      float pn0 = xb[ns] - xc0;
      float pn1 = xb[HW_ + ns] - xc1;
      float pn2 = xb[2 * HW_ + ns] - xc2;
      float pn3 = xb[3 * HW_ + ns] - xc3;
      acc[32] += 1.f;
#pragma unroll
      for (int o = 0; o < 8; o++) {
        float ta = pn0 * w1[o * 4] + pn1 * w1[o * 4 + 1] + pn2 * w1[o * 4 + 2] + pn3 * w1[o * 4 + 3];
        acc[o] += ta; acc[8 + o] += ta * ta;
        float tg = pn0 * g1[o * 4] + pn1 * g1[o * 4 + 1] + pn2 * g1[o * 4 + 2] + pn3 * g1[o * 4 + 3];
        acc[16 + o] += tg; acc[24 + o] += tg * tg;
      }
    }
  }
  __shared__ float red[4][34];
  int lane = threadIdx.x & 63, wave = threadIdx.x >> 6;
#pragma unroll
  for (int i = 0; i < 34; i++) {
    float rv = wred(acc[i]);
    if (lane == 0) red[wave][i] = rv;
  }
  __syncthreads();
  if (threadIdx.x < 34)
    atomicAdd(&ws[threadIdx.x],
              red[0][threadIdx.x] + red[1][threadIdx.x] + red[2][threadIdx.x] + red[3][threadIdx.x]);
}

// ---- K2: stats2, same 2-threads/pixel split ----
__global__ __launch_bounds__(256) void k_stats2(
    const float* __restrict__ x, const float* __restrict__ mask,
    const float* __restrict__ g1, const float* __restrict__ gbn1_g,
    const float* __restrict__ gbn1_b, const float* __restrict__ g2,
    float* __restrict__ ws) {
  __shared__ float sc[8], sh[8];
  if (threadIdx.x < 8) {
    int o = threadIdx.x;
    float n = fmaxf(ws[32], 1.f);
    float mean = ws[16 + o] / n;
    float var = ws[24 + o] / n - mean * mean;
    float s_ = gbn1_g[o] * rsqrtf(var + EPS);
    sc[o] = s_; sh[o] = gbn1_b[o] - mean * s_;
  }
  __syncthreads();

  int half = blockIdx.x >> 9;
  int p = swz_tile(blockIdx.x & 511) * 256 + threadIdx.x;
  int b = p >> 16, s = p & (HW_ - 1);
  int h = s >> 10, w = s & (W_ - 1);
  const float* xb = x + (size_t)b * C_ * HW_;
  const float* mb = mask + (size_t)b * HW_;
  float xc0 = xb[s], xc1 = xb[HW_ + s], xc2 = xb[2 * HW_ + s], xc3 = xb[3 * HW_ + s];

  float acc2[16];
#pragma unroll
  for (int i = 0; i < 16; i++) acc2[i] = 0.f;

#pragma unroll
  for (int k = 0; k < 9; k++) {
    bool mine = (k < 5) ? (half == 0) : (half == 1);
    if (!mine) continue;
    int di = k / 3 - 1, dj = k % 3 - 1;
    int hh = h + di, ww = w + dj;
    bool inb = ((unsigned)hh < (unsigned)H_) && ((unsigned)ww < (unsigned)W_);
    int ns = hh * W_ + ww;
    float mval = inb ? mb[ns] : 0.f;
    if (mval > 0.f) {
      float pn0 = xb[ns] - xc0;
      float pn1 = xb[HW_ + ns] - xc1;
      float pn2 = xb[2 * HW_ + ns] - xc2;
      float pn3 = xb[3 * HW_ + ns] - xc3;
      float gb[8];
#pragma unroll
      for (int o = 0; o < 8; o++) {
        float tg = pn0 * g1[o * 4] + pn1 * g1[o * 4 + 1] + pn2 * g1[o * 4 + 2] + pn3 * g1[o * 4 + 3];
        gb[o] = fmaxf(sc[o] * tg + sh[o], 0.f);
      }
#pragma unroll
      for (int j = 0; j < 8; j++) {
        float t2 = 0.f;
#pragma unroll
        for (int o = 0; o < 8; o++) t2 += gb[o] * g2[j * 8 + o];
        acc2[j] += t2; acc2[8 + j] += t2 * t2;
      }
    }
  }
  __shared__ float red[4][16];
  int lane = threadIdx.x & 63, wave = threadIdx.x >> 6;
#pragma unroll
  for (int i = 0; i < 16; i++) {
    float rv = wred(acc2[i]);
    if (lane == 0) red[wave][i] = rv;
  }
  __syncthreads();
  if (threadIdx.x < 16)
    atomicAdd(&ws[40 + threadIdx.x],
              red[0][threadIdx.x] + red[1][threadIdx.x] + red[2][threadIdx.x] + red[3][threadIdx.x]);
}

// --------- K3: fused kernel, 512 threads / 256 pixels (2 threads per pixel) --
// half 0: neighbors k=0..4; half 1: k=5..8. fagg split by channel (32 each).
// GEMM: 8 waves = 4 m-groups x 2 n-groups.
__global__ __launch_bounds__(512, 4) void k_fused(
    const float* __restrict__ x, const float* __restrict__ mask,
    const float* __restrict__ w1, const float* __restrict__ bn1_g,
    const float* __restrict__ bn1_b, const float* __restrict__ w2,
    const float* __restrict__ b2, const float* __restrict__ g1,
    const float* __restrict__ gbn1_g, const float* __restrict__ gbn1_b,
    const float* __restrict__ g2, const float* __restrict__ gbn2_g,
    const float* __restrict__ gbn2_b, const float* __restrict__ w_agg,
    const float* __restrict__ ws, float* __restrict__ out_pre,
    float* __restrict__ wsum) {
  __shared__ uint4 vecA[17][256];   // 69.6 KB : K-major bf16 chunks
  __shared__ float evb[9][256];     // 9 KB   : softmax logit exchange
  __shared__ float sA[8], hA[8], sG1[8], hG1[8], sG2[8], hG2[8];

  if (threadIdx.x < 24) {
    int o = threadIdx.x & 7;
    float n = fmaxf(ws[32], 1.f);
    float sum, sum2, gma, bta;
    if (threadIdx.x < 8)       { sum = ws[o];      sum2 = ws[8 + o];  gma = bn1_g[o];  bta = bn1_b[o]; }
    else if (threadIdx.x < 16) { sum = ws[16 + o]; sum2 = ws[24 + o]; gma = gbn1_g[o]; bta = gbn1_b[o]; }
    else                       { sum = ws[40 + o]; sum2 = ws[48 + o]; gma = gbn2_g[o]; bta = gbn2_b[o]; }
    float mean = sum / n, var = sum2 / n - mean * mean;
    float s_ = gma * rsqrtf(var + EPS);
    float sft = bta - mean * s_;
    if (threadIdx.x < 8)       { sA[o] = s_;  hA[o] = sft; }
    else if (threadIdx.x < 16) { sG1[o] = s_; hG1[o] = sft; }
    else                       { sG2[o] = s_; hG2[o] = sft; }
  }
  __syncthreads();

  int tid = threadIdx.x;
  int half = tid >> 8;      // 0: k 0..4, 1: k 5..8  (wave-uniform)
  int pix = tid & 255;
  int tile = swz_tile(blockIdx.x);
  int p0 = tile * 256;
  int p = p0 + pix;
  int b = p >> 16, s = p & (HW_ - 1);
  int h = s >> 10, w = s & (W_ - 1);
  const float* xb = x + (size_t)b * C_ * HW_;
  const float* mb = mask + (size_t)b * HW_;
  float xc0 = xb[s], xc1 = xb[HW_ + s], xc2 = xb[2 * HW_ + s], xc3 = xb[3 * HW_ + s];
  float b2v = b2[0];

  // ---- phase 1: softmax logits for my neighbors ----
  unsigned mbits = 0u;
#pragma unroll
  for (int k = 0; k < 9; k++) {
    bool mine = (k < 5) ? (half == 0) : (half == 1);
    if (!mine) continue;
    int di = k / 3 - 1, dj = k % 3 - 1;
    int hh = h + di, ww = w + dj;
    bool inb = ((unsigned)hh < (unsigned)H_) && ((unsigned)ww < (unsigned)W_);
    int ns = hh * W_ + ww;
    float mval = inb ? mb[ns] : 0.f;
    float wp = 0.f;
    if (mval > 0.f) {
      mbits |= (1u << k);
      float pn0 = xb[ns] - xc0;
      float pn1 = xb[HW_ + ns] - xc1;
      float pn2 = xb[2 * HW_ + ns] - xc2;
      float pn3 = xb[3 * HW_ + ns] - xc3;
      float accw = 0.f;
#pragma unroll
      for (int o = 0; o < 8; o++) {
        float ta = pn0 * w1[o * 4] + pn1 * w1[o * 4 + 1] + pn2 * w1[o * 4 + 2] + pn3 * w1[o * 4 + 3];
        accw += fmaxf(sA[o] * ta + hA[o], 0.f) * w2[o];
      }
      wp = accw + b2v;
    }
    evb[k][pix] = wp;
  }
  __syncthreads();

  // ---- phase 2: both halves compute identical softmax weights ----
  float ev[9];
  float mx = -1e30f;
#pragma unroll
  for (int k = 0; k < 9; k++) { ev[k] = evb[k][pix]; mx = fmaxf(mx, ev[k]); }
  float den = 0.f;
#pragma unroll
  for (int k = 0; k < 9; k++) { ev[k] = __expf(ev[k] - mx); den += ev[k]; }
  float inv = 1.f / den;

  // ---- phase 3: g-vec for my neighbors ----
#pragma unroll
  for (int k = 0; k < 9; k++) {
    bool mine = (k < 5) ? (half == 0) : (half == 1);
    if (!mine) continue;
    uint4 pk; pk.x = pk.y = pk.z = pk.w = 0u;
    if ((mbits >> k) & 1u) {
      int di = k / 3 - 1, dj = k % 3 - 1;
      int ns = (h + di) * W_ + (w + dj);
      float wt = ev[k] * inv;
      float pn0 = xb[ns] - xc0;
      float pn1 = xb[HW_ + ns] - xc1;
      float pn2 = xb[2 * HW_ + ns] - xc2;
      float pn3 = xb[3 * HW_ + ns] - xc3;
      float gb[8];
#pragma unroll
      for (int o = 0; o < 8; o++) {
        float tg = pn0 * g1[o * 4] + pn1 * g1[o * 4 + 1] + pn2 * g1[o * 4 + 2] + pn3 * g1[o * 4 + 3];
        gb[o] = fmaxf(sG1[o] * tg + hG1[o], 0.f);
      }
      float gv[8];
#pragma unroll
      for (int j = 0; j < 8; j++) {
        float t2 = 0.f;
#pragma unroll
        for (int o = 0; o < 8; o++) t2 += gb[o] * g2[j * 8 + o];
        float gg = fmaxf(sG2[j] * t2 + hG2[j], 0.f);
        gv[j] = wt * gg;
      }
      pk.x = pack2(gv[0], gv[1]); pk.y = pack2(gv[2], gv[3]);
      pk.z = pack2(gv[4], gv[5]); pk.w = pack2(gv[6], gv[7]);
    }
    vecA[8 + k][pix] = pk;
  }

  // ---- phase 4: fagg over my 32 channels, all 9 neighbors ----
  float facc[32];
#pragma unroll
  for (int c = 0; c < 32; c++) facc[c] = 0.f;
#pragma unroll
  for (int k = 0; k < 9; k++) {
    int di = k / 3 - 1, dj = k % 3 - 1;
    int hh = h + di, ww = w + dj;
    bool inb = ((unsigned)hh < (unsigned)H_) && ((unsigned)ww < (unsigned)W_);
    if (inb) {
      int ns = hh * W_ + ww;
      float wt = ev[k] * inv;
      const float* xf = xb + (size_t)(4 + half * 32) * HW_ + ns;
#pragma unroll
      for (int c = 0; c < 32; c++) facc[c] += wt * xf[c * HW_];
    }
  }
#pragma unroll
  for (int c0 = 0; c0 < 32; c0 += 8) {
    uint4 pk;
    pk.x = pack2(facc[c0], facc[c0 + 1]);     pk.y = pack2(facc[c0 + 2], facc[c0 + 3]);
    pk.z = pack2(facc[c0 + 4], facc[c0 + 5]); pk.w = pack2(facc[c0 + 6], facc[c0 + 7]);
    vecA[(half * 32 + c0) >> 3][pix] = pk;
  }
  __syncthreads();

  // ---- GEMM: D[pixel 256][chan 64] = vecA @ w_agg^T, 8 waves (4 m x 2 n) ----
  int lane = tid & 63, wave = tid >> 6;
  int q = lane >> 4, r = lane & 15;
  int wr = wave >> 1, wc = wave & 1;

  short8 Bf[2][5];
#pragma unroll
  for (int nt = 0; nt < 2; nt++) {
    int n = wc * 32 + nt * 16 + r;
#pragma unroll
    for (int ks = 0; ks < 5; ks++) {
      int k0 = ks * 32 + q * 8;
      uint4 pk; pk.x = pk.y = pk.z = pk.w = 0u;
      if (k0 < 136) {
        float4 f0 = *reinterpret_cast<const float4*>(w_agg + n * 136 + k0);
        float4 f1 = *reinterpret_cast<const float4*>(w_agg + n * 136 + k0 + 4);
        pk.x = pack2(f0.x, f0.y); pk.y = pack2(f0.z, f0.w);
        pk.z = pack2(f1.x, f1.y); pk.w = pack2(f1.z, f1.w);
      }
      Bf[nt][ks] = *reinterpret_cast<short8*>(&pk);
    }
  }

  floatx4 acc[4][2];
#pragma unroll
  for (int m = 0; m < 4; m++)
#pragma unroll
    for (int nt = 0; nt < 2; nt++) acc[m][nt] = (floatx4){0.f, 0.f, 0.f, 0.f};

#pragma unroll
  for (int m = 0; m < 4; m++) {
    int pixm = (wr * 4 + m) * 16 + r;
    short8 Af[5];
#pragma unroll
    for (int ks = 0; ks < 5; ks++) {
      int chunk = ks * 4 + q;
      if (chunk < 17)
        Af[ks] = *reinterpret_cast<const short8*>(&vecA[chunk][pixm]);
      else
        Af[ks] = (short8){0, 0, 0, 0, 0, 0, 0, 0};
    }
#pragma unroll
    for (int nt = 0; nt < 2; nt++)
#pragma unroll
      for (int ks = 0; ks < 5; ks++)
        acc[m][nt] = __builtin_amdgcn_mfma_f32_16x16x32_bf16(Af[ks], Bf[nt][ks], acc[m][nt], 0, 0, 0);
  }

  // ---- store + masked abn partial sums ----
  float aS[2] = {0.f, 0.f}, aQ[2] = {0.f, 0.f};
  int s0 = p0 & (HW_ - 1);
#pragma unroll
  for (int m = 0; m < 4; m++) {
    int mt = wr * 4 + m;
    int srow = s0 + mt * 16 + q * 4;
    float4 mv = *reinterpret_cast<const float4*>(mb + srow);
    float m0 = (mv.x > 0.f) ? 1.f : 0.f, m1 = (mv.y > 0.f) ? 1.f : 0.f;
    float m2 = (mv.z > 0.f) ? 1.f : 0.f, m3 = (mv.w > 0.f) ? 1.f : 0.f;
#pragma unroll
    for (int nt = 0; nt < 2; nt++) {
      int ch = wc * 32 + nt * 16 + r;
      float4 ov;
      ov.x = acc[m][nt][0]; ov.y = acc[m][nt][1];
      ov.z = acc[m][nt][2]; ov.w = acc[m][nt][3];
      aS[nt] += ov.x * m0 + ov.y * m1 + ov.z * m2 + ov.w * m3;
      aQ[nt] += ov.x * ov.x * m0 + ov.y * ov.y * m1 + ov.z * ov.z * m2 + ov.w * ov.w * m3;
      *reinterpret_cast<float4*>(out_pre + ((size_t)(b * 64 + ch)) * HW_ + srow) = ov;
    }
  }

  __syncthreads();  // all vecA ds_reads done; reuse LDS for reduction
  float* rS = (float*)&vecA[0][0];   // [8 waves][2 nt][16 r]
  float* rQ = rS + 256;
#pragma unroll
  for (int nt = 0; nt < 2; nt++) {
    float v1 = aS[nt], v2 = aQ[nt];
    v1 += __shfl_xor(v1, 16); v1 += __shfl_xor(v1, 32);
    v2 += __shfl_xor(v2, 16); v2 += __shfl_xor(v2, 32);
    if (lane < 16) { rS[wave * 32 + nt * 16 + lane] = v1; rQ[wave * 32 + nt * 16 + lane] = v2; }
  }
  __syncthreads();
  if (tid < 64) {
    int c = tid;
    int wc_ = c >> 5, nt_ = (c >> 4) & 1, r_ = c & 15;
    float s1 = 0.f, s2 = 0.f;
#pragma unroll
    for (int wr_ = 0; wr_ < 4; wr_++) {
      int idx = (wr_ * 2 + wc_) * 32 + nt_ * 16 + r_;
      s1 += rS[idx]; s2 += rQ[idx];
    }
    atomicAdd(&wsum[64 + c], s1);
    atomicAdd(&wsum[128 + c], s2);
  }
}

// ---------------- K4: abn apply + relu + center-mask zero -------------------
__global__ __launch_bounds__(256) void k_final(
    const float* __restrict__ out_pre, const float* __restrict__ mask,
    const float* __restrict__ abn_g, const float* __restrict__ abn_b,
    const float* __restrict__ ws, float* __restrict__ out) {
  __shared__ float sc[64], sh[64];
  if (threadIdx.x < 64) {
    int c = threadIdx.x;
    float n0 = fmaxf(ws[33], 1.f);
    float mean = ws[64 + c] / n0;
    float var = ws[128 + c] / n0 - mean * mean;
    float s_ = abn_g[c] * rsqrtf(var + EPS);
    sc[c] = s_; sh[c] = abn_b[c] - mean * s_;
  }
  __syncthreads();
  int i4 = (blockIdx.x * 256 + threadIdx.x) * 4;
  if (i4 >= B_ * 64 * HW_) return;
  int c = (i4 >> 16) & 63;
  int b = i4 >> 22;
  int s = i4 & (HW_ - 1);
  float4 v = *reinterpret_cast<const float4*>(out_pre + i4);
  float4 m = *reinterpret_cast<const float4*>(mask + (size_t)b * HW_ + s);
  float4 o;
  o.x = (m.x > 0.f) ? fmaxf(v.x * sc[c] + sh[c], 0.f) : 0.f;
  o.y = (m.y > 0.f) ? fmaxf(v.y * sc[c] + sh[c], 0.f) : 0.f;
  o.z = (m.z > 0.f) ? fmaxf(v.z * sc[c] + sh[c], 0.f) : 0.f;
  o.w = (m.w > 0.f) ? fmaxf(v.w * sc[c] + sh[c], 0.f) : 0.f;
  *reinterpret_cast<float4*>(out + i4) = o;
}

extern "C" void kernel_launch(void* const* d_in, const int* in_sizes, int n_in,
                              void* d_out, int out_size, void* d_ws, size_t ws_size,
                              hipStream_t stream) {
  const float* x      = (const float*)d_in[0];
  const float* mask   = (const float*)d_in[1];
  const float* w1     = (const float*)d_in[2];
  const float* bn1_g  = (const float*)d_in[3];
  const float* bn1_b  = (const float*)d_in[4];
  const float* w2     = (const float*)d_in[5];
  const float* b2     = (const float*)d_in[6];
  const float* g1     = (const float*)d_in[7];
  const float* gbn1_g = (const float*)d_in[8];
  const float* gbn1_b = (const float*)d_in[9];
  const float* g2     = (const float*)d_in[10];
  const float* gbn2_g = (const float*)d_in[11];
  const float* gbn2_b = (const float*)d_in[12];
  const float* w_agg  = (const float*)d_in[13];
  const float* abn_g  = (const float*)d_in[14];
  const float* abn_b  = (const float*)d_in[15];
  float* out = (float*)d_out;

  size_t need = 1024 + (size_t)NPIX * 64 * 4;
  if (ws_size < need) return;

  float* wsf = (float*)d_ws;
  float* out_pre = (float*)((char*)d_ws + 1024);

  hipMemsetAsync(d_ws, 0, 1024, stream);
  k_stats1<<<1024, 256, 0, stream>>>(x, mask, w1, g1, wsf);
  k_stats2<<<1024, 256, 0, stream>>>(x, mask, g1, gbn1_g, gbn1_b, g2, wsf);
  k_fused<<<512, 512, 0, stream>>>(x, mask, w1, bn1_g, bn1_b, w2, b2, g1,
                                   gbn1_g, gbn1_b, g2, gbn2_g, gbn2_b, w_agg,
                                   wsf, out_pre, wsf);
  k_final<<<8192, 256, 0, stream>>>(out_pre, mask, abn_g, abn_b, wsf, out);
}